// Round 4
// baseline (318.339 us; speedup 1.0000x reference)
//
#include <hip/hip_runtime.h>
#include <hip/hip_bf16.h>
#include <stdint.h>

#define D_IN    512
#define NTOT    32896
#define BATCH   4096
#define NWG_GEMM 4112    // 16 m-tiles (BM=256) * 257 n-tiles (BN=128)
#define XCD_CHUNK 514    // NWG_GEMM / 8
#define NT_K    8        // 512 / BK=64

typedef __attribute__((ext_vector_type(8))) short short8;
typedef __attribute__((ext_vector_type(4))) float f32x4;

__device__ __forceinline__ unsigned short f2bf(float f) {
    union { float f; uint32_t u; } v; v.f = f;
    return (unsigned short)((v.u + 0x7fffu + ((v.u >> 16) & 1u)) >> 16);
}

// x [BATCH][D_IN] fp32 -> bf16, same layout (K contiguous)
__global__ __launch_bounds__(256) void convx_kernel(const float* __restrict__ x,
                                                    unsigned short* __restrict__ xb) {
    int tid = blockIdx.x * 256 + threadIdx.x;
    const f32x4* xv = (const f32x4*)x;
    f32x4 a = __builtin_nontemporal_load(xv + 2 * tid);
    f32x4 c = __builtin_nontemporal_load(xv + 2 * tid + 1);
    short8 o;
    o[0] = (short)f2bf(a[0]); o[1] = (short)f2bf(a[1]);
    o[2] = (short)f2bf(a[2]); o[3] = (short)f2bf(a[3]);
    o[4] = (short)f2bf(c[0]); o[5] = (short)f2bf(c[1]);
    o[6] = (short)f2bf(c[2]); o[7] = (short)f2bf(c[3]);
    ((short8*)xb)[tid] = o;
}

// W [D_IN][NTOT] fp32 -> k-packed bf16: Wp[g][n][r] = W[g*8+r][n], g in [0,64)
__global__ __launch_bounds__(256) void convw_kernel(const float* __restrict__ W,
                                                    unsigned short* __restrict__ wp) {
    int tid = blockIdx.x * 256 + threadIdx.x;
    int g = tid / NTOT;
    int n = tid - g * NTOT;
    const float* src = W + (size_t)g * 8u * NTOT + n;
    short8 o;
#pragma unroll
    for (int r = 0; r < 8; ++r) o[r] = (short)f2bf(__builtin_nontemporal_load(src + (size_t)r * NTOT));
    ((short8*)wp)[(size_t)g * NTOT + n] = o;
}

__device__ __forceinline__ void gload16(const void* g, void* l) {
    __builtin_amdgcn_global_load_lds(
        (const __attribute__((address_space(1))) void*)g,
        (__attribute__((address_space(3))) void*)l, 16, 0, 0);
}

// C[M][N] = Ab * Wp + bias. BM=256, BN=128, BK=64.
// 8 waves (4m x 2n), wave-tile 64x64 = 4x4 frags of 16x16x32 bf16 MFMA.
// 3-buffer LDS pipeline (144 KB dynamic), prefetch distance 2, counted vmcnt:
// iter t issues tile t+2 (6 loads/wave), waits vmcnt(12) -> exactly drains
// tile t's loads while tiles t+1,t+2 stay in flight across the barrier (T4).
// k-packed LDS layout keeps both global_load_lds (linear dest) and
// ds_read_b128 fragment reads conflict-free (measured BANK_CONFLICT=0).
__global__ __launch_bounds__(512, 2) void gemm_kernel(
        const unsigned short* __restrict__ Ab,   // [BATCH][D_IN] bf16
        const unsigned short* __restrict__ Bp,   // [64][NTOT][8] bf16 k-packed
        const float* __restrict__ bias,          // [NTOT] fp32
        float* __restrict__ C) {                 // [BATCH][NTOT] fp32
    extern __shared__ char smem[];
    // sA[buf][g][row] : 3 x 8 x 256 short8 = 96 KB
    // sB[buf][g][col] : 3 x 8 x 128 short8 = 48 KB
    short8 (*sA)[8][256] = reinterpret_cast<short8(*)[8][256]>(smem);
    short8 (*sB)[8][128] = reinterpret_cast<short8(*)[8][128]>(smem + 3 * 8 * 256 * 16);

    const int bid = (int)blockIdx.x;
    // bijective chunked XCD swizzle (4112 % 8 == 0); mt-fastest so the 16
    // m-blocks sharing one 128-col W panel are consecutive on one XCD.
    const int wg  = (bid & 7) * XCD_CHUNK + (bid >> 3);
    const int mt  = wg & 15;        // 16 m-tiles
    const int nt  = wg >> 4;        // 257 n-tiles
    const int brow = mt * 256;
    const int bcol = nt * 128;

    const int tid  = (int)threadIdx.x;
    const int lane = tid & 63;
    const int w    = tid >> 6;      // wave 0..7: stages k-group w
    const int wm   = w >> 1;        // 0..3
    const int wn   = w & 1;         // 0..1

    f32x4 acc[4][4] = {};

    // Per-wave staging bases. A: 4 loads (rows j*64+lane), B: 2 loads.
    const unsigned short* aSrc = Ab + (size_t)(brow + lane) * D_IN + w * 8;
    const unsigned short* bSrc = Bp + ((size_t)w * NTOT + bcol + lane) * 8;

#define STAGE(t, c) do {                                                      \
    const unsigned short* as_ = aSrc + (size_t)(t) * 64;                      \
    gload16(as_,                       (void*)&sA[c][w][0]);                  \
    gload16(as_ + (size_t) 64 * D_IN,  (void*)&sA[c][w][64]);                 \
    gload16(as_ + (size_t)128 * D_IN,  (void*)&sA[c][w][128]);                \
    gload16(as_ + (size_t)192 * D_IN,  (void*)&sA[c][w][192]);                \
    const unsigned short* bs_ = bSrc + (size_t)(t) * 8 * NTOT * 8;            \
    gload16(bs_,           (void*)&sB[c][w][0]);                              \
    gload16(bs_ + 64 * 8,  (void*)&sB[c][w][64]);                             \
} while (0)

    // Prologue: tiles 0,1 in flight (12 loads/wave).
    STAGE(0, 0);
    STAGE(1, 1);

    const int g  = lane >> 4;
    const int fr = lane & 15;

#pragma unroll
    for (int t = 0; t < NT_K; ++t) {
        const int c = t % 3;
        if (t < NT_K - 2) STAGE(t + 2, (t + 2) % 3);
        // counted waits: drain exactly tile t, keep newer loads in flight
        if (t < NT_K - 2)      asm volatile("s_waitcnt vmcnt(12)" ::: "memory");
        else if (t == NT_K - 2) asm volatile("s_waitcnt vmcnt(6)" ::: "memory");
        else                    asm volatile("s_waitcnt vmcnt(0)" ::: "memory");
        __builtin_amdgcn_sched_barrier(0);
        __builtin_amdgcn_s_barrier();     // tile t resident everywhere

#pragma unroll
        for (int kk = 0; kk < 2; ++kk) {
            short8 bF[4];
#pragma unroll
            for (int n = 0; n < 4; ++n) bF[n] = sB[c][kk * 4 + g][wn * 64 + n * 16 + fr];
#pragma unroll
            for (int mh = 0; mh < 2; ++mh) {
                short8 aF[2];
#pragma unroll
                for (int mi = 0; mi < 2; ++mi)
                    aF[mi] = sA[c][kk * 4 + g][wm * 64 + (mh * 2 + mi) * 16 + fr];
                __builtin_amdgcn_s_setprio(1);
#pragma unroll
                for (int mi = 0; mi < 2; ++mi)
#pragma unroll
                    for (int n = 0; n < 4; ++n)
                        acc[mh * 2 + mi][n] = __builtin_amdgcn_mfma_f32_16x16x32_bf16(
                            aF[mi], bF[n], acc[mh * 2 + mi][n], 0, 0, 0);
                __builtin_amdgcn_s_setprio(0);
            }
        }
        __builtin_amdgcn_s_barrier();     // all reads of buf c done before
                                          // iter t+1 restages into it
    }
#undef STAGE

    // Epilogue: C/D layout col = lane&15, row = (lane>>4)*4 + reg.
    // Nontemporal stores (write-once output, no write-allocate fetch).
    const int rowb = brow + wm * 64 + (lane >> 4) * 4;
    const int colb = bcol + wn * 64 + fr;
    float bv[4];
#pragma unroll
    for (int n = 0; n < 4; ++n) bv[n] = bias[colb + n * 16];
#pragma unroll
    for (int m = 0; m < 4; ++m) {
#pragma unroll
        for (int q = 0; q < 4; ++q) {
            float* rowp = C + (size_t)(rowb + m * 16 + q) * NTOT + colb;
#pragma unroll
            for (int n = 0; n < 4; ++n)
                __builtin_nontemporal_store(acc[m][n][q] + bv[n], rowp + n * 16);
        }
    }
}

extern "C" void kernel_launch(void* const* d_in, const int* in_sizes, int n_in,
                              void* d_out, int out_size, void* d_ws, size_t ws_size,
                              hipStream_t stream) {
    const float* x = (const float*)d_in[0];
    const float* W = (const float*)d_in[1];
    const float* b = (const float*)d_in[2];
    float* out = (float*)d_out;

    unsigned short* xb = (unsigned short*)d_ws;               // 4 MB
    unsigned short* wp = xb + (size_t)BATCH * D_IN;           // +33.7 MB

    convx_kernel<<<(BATCH * D_IN / 8) / 256, 256, 0, stream>>>(x, xb);
    convw_kernel<<<((D_IN / 8) * NTOT) / 256, 256, 0, stream>>>(W, wp);

    const int lds_bytes = 3 * (8 * 256 + 8 * 128) * 16;       // 147456
    hipFuncSetAttribute((const void*)gemm_kernel,
                        hipFuncAttributeMaxDynamicSharedMemorySize, lds_bytes);
    gemm_kernel<<<NWG_GEMM, 512, lds_bytes, stream>>>(xb, wp, b, out);
}

// Round 5
// 298.337 us; speedup vs baseline: 1.0670x; 1.0670x over previous
//
#include <hip/hip_runtime.h>
#include <hip/hip_bf16.h>
#include <stdint.h>

#define D_IN    512
#define NTOT    32896
#define BATCH   4096
#define BM      512
#define BN      128
#define BK      32
#define NT_K    16       // 512 / BK
#define NWG_GEMM 2056    // 8 m-tiles * 257 n-tiles

typedef __attribute__((ext_vector_type(8))) short short8;
typedef __attribute__((ext_vector_type(4))) float f32x4;

__device__ __forceinline__ unsigned short f2bf(float f) {
    union { float f; uint32_t u; } v; v.f = f;
    return (unsigned short)((v.u + 0x7fffu + ((v.u >> 16) & 1u)) >> 16);
}

// x [BATCH][D_IN] fp32 -> bf16, same layout (K contiguous)
__global__ __launch_bounds__(256) void convx_kernel(const float* __restrict__ x,
                                                    unsigned short* __restrict__ xb) {
    int tid = blockIdx.x * 256 + threadIdx.x;
    const f32x4* xv = (const f32x4*)x;
    f32x4 a = __builtin_nontemporal_load(xv + 2 * tid);
    f32x4 c = __builtin_nontemporal_load(xv + 2 * tid + 1);
    short8 o;
    o[0] = (short)f2bf(a[0]); o[1] = (short)f2bf(a[1]);
    o[2] = (short)f2bf(a[2]); o[3] = (short)f2bf(a[3]);
    o[4] = (short)f2bf(c[0]); o[5] = (short)f2bf(c[1]);
    o[6] = (short)f2bf(c[2]); o[7] = (short)f2bf(c[3]);
    ((short8*)xb)[tid] = o;
}

// W [D_IN][NTOT] fp32 -> k-packed bf16: Wp[g][n][r] = W[g*8+r][n], g in [0,64)
__global__ __launch_bounds__(256) void convw_kernel(const float* __restrict__ W,
                                                    unsigned short* __restrict__ wp) {
    int tid = blockIdx.x * 256 + threadIdx.x;
    int g = tid / NTOT;
    int n = tid - g * NTOT;
    const float* src = W + (size_t)g * 8u * NTOT + n;
    short8 o;
#pragma unroll
    for (int r = 0; r < 8; ++r) o[r] = (short)f2bf(__builtin_nontemporal_load(src + (size_t)r * NTOT));
    ((short8*)wp)[(size_t)g * NTOT + n] = o;
}

__device__ __forceinline__ void gload16(const void* g, void* l) {
    __builtin_amdgcn_global_load_lds(
        (const __attribute__((address_space(1))) void*)g,
        (__attribute__((address_space(3))) void*)l, 16, 0, 0);
}

// compiler memory fence + raw barrier (NO vmcnt(0) drain, unlike __syncthreads)
#define BAR() do { asm volatile("" ::: "memory"); \
                   __builtin_amdgcn_s_barrier();  \
                   asm volatile("" ::: "memory"); } while (0)

// C[M][N] = Ab * Wp + bias. BM=512, BN=128, BK=32, 16 K-tiles.
// 8 waves (4m x 2n), wave-tile 128x64 = 8x4 frags of 16x16x32 bf16 MFMA.
// 3 LDS buffers (120 KB), 2-tile prefetch lead, 2 fine phases per K-tile
// {ds_read subtile | issue stage loads | barrier | setprio+16 MFMA | barrier},
// counted s_waitcnt vmcnt(5) ONCE per K-tile (never 0 in steady state).
// k-packed LDS keeps global_load_lds linear-dest legal AND ds_read_b128
// conflict-free (BANK_CONFLICT=0 measured in R1).
// mt = bid&7: each XCD owns one 512-row A tile (512 KB, L2-resident),
// streams all B panels; cross-XCD W re-reads absorbed by L3.
__global__ __launch_bounds__(512, 2) void gemm_kernel(
        const unsigned short* __restrict__ Ab,   // [BATCH][D_IN] bf16
        const unsigned short* __restrict__ Bp,   // [64][NTOT][8] bf16 k-packed
        const float* __restrict__ bias,          // [NTOT] fp32
        float* __restrict__ C) {                 // [BATCH][NTOT] fp32
    extern __shared__ char smem[];
    // sA[buf][g][row] : 3 x 4 x 512 short8 = 96 KB
    // sB[buf][g][col] : 3 x 4 x 128 short8 = 24 KB
    short8 (*sA)[4][BM] = reinterpret_cast<short8(*)[4][BM]>(smem);
    short8 (*sB)[4][BN] = reinterpret_cast<short8(*)[4][BN]>(smem + 3 * 4 * BM * 16);

    const int bid  = (int)blockIdx.x;
    const int brow = (bid & 7) * BM;        // mt = bid&7 -> XCD-exclusive A tile
    const int bcol = (bid >> 3) * BN;       // nt streams in dispatch order

    const int tid  = (int)threadIdx.x;
    const int lane = tid & 63;
    const int w    = tid >> 6;      // wave 0..7
    const int wm   = w >> 1;        // 0..3 : m-offset wm*128
    const int wn   = w & 1;         // 0..1 : n-offset wn*64

    // staging ownership: wave w stages k-group gs for A row-blocks
    // {half,2+half,4+half,6+half} and B col-block half  -> 5 loads/wave/tile
    const int gs   = w & 3;
    const int half = w >> 2;

    const int g  = lane >> 4;       // fragment k-group
    const int fr = lane & 15;       // fragment row/col

    f32x4 acc[8][4] = {};

#define STAGE_A(t, c, rb) gload16(Ab + (size_t)(brow + (rb) * 64 + lane) * D_IN + (t) * BK + gs * 8, \
                                  (void*)&sA[c][gs][(rb) * 64])
#define STAGE_B(t, c, cb) gload16(Bp + ((size_t)((t) * 4 + gs) * NTOT + bcol + (cb) * 64 + lane) * 8, \
                                  (void*)&sB[c][gs][(cb) * 64])

    // prologue: stage tiles 0 and 1 (10 loads in flight)
    STAGE_A(0, 0, half); STAGE_A(0, 0, 2 + half);
    STAGE_A(0, 0, 4 + half); STAGE_A(0, 0, 6 + half);
    STAGE_B(0, 0, half);
    STAGE_A(1, 1, half); STAGE_A(1, 1, 2 + half);
    STAGE_A(1, 1, 4 + half); STAGE_A(1, 1, 6 + half);
    STAGE_B(1, 1, half);
    asm volatile("s_waitcnt vmcnt(5)" ::: "memory");   // tile 0 resident
    BAR();

#pragma unroll
    for (int t = 0; t < NT_K; ++t) {
        const int c  = t % 3;
        const int cs = (t + 2) % 3;

        // ---------- phase 0 ----------
        short8 bF[4], aF[8];
#pragma unroll
        for (int n = 0; n < 4; ++n) bF[n] = sB[c][g][wn * 64 + n * 16 + fr];
#pragma unroll
        for (int m = 0; m < 4; ++m) aF[m] = sA[c][g][wm * 128 + m * 16 + fr];
        if (t < NT_K - 2) {
            STAGE_A(t + 2, cs, half);
            STAGE_A(t + 2, cs, 2 + half);
            STAGE_B(t + 2, cs, half);
        }
        BAR();
        __builtin_amdgcn_s_setprio(1);
#pragma unroll
        for (int m = 0; m < 4; ++m)
#pragma unroll
            for (int n = 0; n < 4; ++n)
                acc[m][n] = __builtin_amdgcn_mfma_f32_16x16x32_bf16(
                    aF[m], bF[n], acc[m][n], 0, 0, 0);
        __builtin_amdgcn_s_setprio(0);
        BAR();

        // ---------- phase 1 ----------
#pragma unroll
        for (int m = 4; m < 8; ++m) aF[m] = sA[c][g][wm * 128 + m * 16 + fr];
        if (t < NT_K - 2) {
            STAGE_A(t + 2, cs, 4 + half);
            STAGE_A(t + 2, cs, 6 + half);
        }
        BAR();
        __builtin_amdgcn_s_setprio(1);
#pragma unroll
        for (int m = 4; m < 8; ++m)
#pragma unroll
            for (int n = 0; n < 4; ++n)
                acc[m][n] = __builtin_amdgcn_mfma_f32_16x16x32_bf16(
                    aF[m], bF[n], acc[m][n], 0, 0, 0);
        __builtin_amdgcn_s_setprio(0);
        // counted drain: tile t+1's 5 loads complete; tile t+2's stay in flight
        if (t < NT_K - 2)       asm volatile("s_waitcnt vmcnt(5)" ::: "memory");
        else if (t == NT_K - 2) asm volatile("s_waitcnt vmcnt(0)" ::: "memory");
        BAR();                  // publishes buffer (t+1)%3
    }
#undef STAGE_A
#undef STAGE_B

    // Epilogue: C/D col = lane&15, row = (lane>>4)*4 + reg (verified R1-R3).
    // Nontemporal dword stores; n-innermost covers 256 B contiguous per row.
    const int rowb = brow + wm * 128 + (lane >> 4) * 4;
    const int colb = bcol + wn * 64 + fr;
    float bv[4];
#pragma unroll
    for (int n = 0; n < 4; ++n) bv[n] = bias[colb + n * 16];
#pragma unroll
    for (int m = 0; m < 8; ++m) {
#pragma unroll
        for (int q = 0; q < 4; ++q) {
            float* rowp = C + (size_t)(rowb + m * 16 + q) * NTOT + colb;
#pragma unroll
            for (int n = 0; n < 4; ++n)
                __builtin_nontemporal_store(acc[m][n][q] + bv[n], rowp + n * 16);
        }
    }
}

extern "C" void kernel_launch(void* const* d_in, const int* in_sizes, int n_in,
                              void* d_out, int out_size, void* d_ws, size_t ws_size,
                              hipStream_t stream) {
    const float* x = (const float*)d_in[0];
    const float* W = (const float*)d_in[1];
    const float* b = (const float*)d_in[2];
    float* out = (float*)d_out;

    unsigned short* xb = (unsigned short*)d_ws;               // 4 MB
    unsigned short* wp = xb + (size_t)BATCH * D_IN;           // +33.7 MB

    convx_kernel<<<(BATCH * D_IN / 8) / 256, 256, 0, stream>>>(x, xb);
    convw_kernel<<<((D_IN / 8) * NTOT) / 256, 256, 0, stream>>>(W, wp);

    const int lds_bytes = 3 * 4 * (BM + BN) * 16;             // 122880
    hipFuncSetAttribute((const void*)gemm_kernel,
                        hipFuncAttributeMaxDynamicSharedMemorySize, lds_bytes);
    gemm_kernel<<<NWG_GEMM, 512, lds_bytes, stream>>>(xb, wp, b, out);
}

// Round 6
// 230.816 us; speedup vs baseline: 1.3792x; 1.2925x over previous
//
#include <hip/hip_runtime.h>
#include <hip/hip_bf16.h>
#include <stdint.h>

#define D_IN    512
#define NTOT    32896
#define BATCH   4096
#define NWG_GEMM 8224   // 32 m-tiles * 257 n-tiles

typedef __attribute__((ext_vector_type(8))) short short8;
typedef __attribute__((ext_vector_type(4))) float f32x4;

__device__ __forceinline__ unsigned short f2bf(float f) {
    union { float f; uint32_t u; } v; v.f = f;
    return (unsigned short)((v.u + 0x7fffu + ((v.u >> 16) & 1u)) >> 16);
}

// x [BATCH][D_IN] fp32 -> bf16, same layout (K contiguous)
__global__ __launch_bounds__(256) void convx_kernel(const float* __restrict__ x,
                                                    unsigned short* __restrict__ xb) {
    int tid = blockIdx.x * 256 + threadIdx.x;
    const f32x4* xv = (const f32x4*)x;
    f32x4 a = __builtin_nontemporal_load(xv + 2 * tid);
    f32x4 c = __builtin_nontemporal_load(xv + 2 * tid + 1);
    short8 o;
    o[0] = (short)f2bf(a[0]); o[1] = (short)f2bf(a[1]);
    o[2] = (short)f2bf(a[2]); o[3] = (short)f2bf(a[3]);
    o[4] = (short)f2bf(c[0]); o[5] = (short)f2bf(c[1]);
    o[6] = (short)f2bf(c[2]); o[7] = (short)f2bf(c[3]);
    ((short8*)xb)[tid] = o;
}

// W [D_IN][NTOT] fp32 -> k-packed bf16: Wp[g][n][r] = W[g*8+r][n], g in [0,64)
__global__ __launch_bounds__(256) void convw_kernel(const float* __restrict__ W,
                                                    unsigned short* __restrict__ wp) {
    int tid = blockIdx.x * 256 + threadIdx.x;
    int g = tid / NTOT;
    int n = tid - g * NTOT;
    const float* src = W + (size_t)g * 8u * NTOT + n;
    short8 o;
#pragma unroll
    for (int r = 0; r < 8; ++r) o[r] = (short)f2bf(__builtin_nontemporal_load(src + (size_t)r * NTOT));
    ((short8*)wp)[(size_t)g * NTOT + n] = o;
}

__device__ __forceinline__ void gload16(const void* g, void* l) {
    __builtin_amdgcn_global_load_lds(
        (const __attribute__((address_space(1))) void*)g,
        (__attribute__((address_space(3))) void*)l, 16, 0, 0);
}

// C[M][N] = Ab * Wp + bias. R3-proven structure: 128x128 tile, BK=32,
// double-buffered LDS (32 KB), 4 waves 2x2, wave-tile 64x64 (4x4 frags of
// 16x16x32 bf16 MFMA). New vs R3:
//  (a) XCD mapping: xcd=bid&7 owns a 4-mt A band (512 KB, L2-resident),
//      sweeps all 257 n-panels; all XCDs sweep nt together -> B hits L3.
//  (b) Epilogue: per-wave LDS transpose (16x68 f32 chunk, wave-private,
//      padded stride -> conflict-free) then nontemporal float4 stores where
//      lanes 0-7 cover one full 128 B line -> no TCC write-allocate fetch.
__global__ __launch_bounds__(256, 3) void gemm_kernel(
        const unsigned short* __restrict__ Ab,   // [BATCH][D_IN] bf16
        const unsigned short* __restrict__ Bp,   // [64][NTOT][8] bf16 k-packed
        const float* __restrict__ bias,          // [NTOT] fp32
        float* __restrict__ C) {                 // [BATCH][NTOT] fp32
    __shared__ __align__(16) char smem_raw[32768];
    short8 (*sA)[4][128] = reinterpret_cast<short8(*)[4][128]>(smem_raw);          // 16 KB
    short8 (*sB)[4][128] = reinterpret_cast<short8(*)[4][128]>(smem_raw + 16384);  // 16 KB

    const int bid = (int)blockIdx.x;
    const int xcd = bid & 7;
    const int j   = bid >> 3;          // 0..1027
    const int mt  = xcd * 4 + (j & 3); // XCD-exclusive 4-tile A band
    const int nt  = j >> 2;            // 0..256, swept in step across XCDs
    const int brow = mt * 128;
    const int bcol = nt * 128;

    const int tid  = (int)threadIdx.x;
    const int lane = tid & 63;
    const int w    = tid >> 6;      // wave 0..3
    const int wr   = w >> 1;        // wave row (0,1)
    const int wc   = w & 1;         // wave col (0,1)

    f32x4 acc[4][4] = {};

    // Staging: wave w owns k-group g=w of both tiles, halves h=0,1.
    const unsigned short* gA0 = Ab + (size_t)(brow + lane) * D_IN + w * 8;
    const unsigned short* gA1 = Ab + (size_t)(brow + 64 + lane) * D_IN + w * 8;
    const unsigned short* gB0 = Bp + ((size_t)w * NTOT + bcol + lane) * 8;
    const unsigned short* gB1 = Bp + ((size_t)w * NTOT + bcol + 64 + lane) * 8;
    const size_t bstep = (size_t)4 * NTOT * 8;   // advance 4 k-groups

    const int g  = lane >> 4;       // k-group of this lane's fragment
    const int fr = lane & 15;       // row (A) / col (B) within fragment

    // --- prologue: stage K-tile 0 into buffer 0 ---
    gload16(gA0, (void*)&sA[0][w][0]);
    gload16(gA1, (void*)&sA[0][w][64]);
    gload16(gB0, (void*)&sB[0][w][0]);
    gload16(gB1, (void*)&sB[0][w][64]);
    gA0 += 32; gA1 += 32; gB0 += bstep; gB1 += bstep;
    __syncthreads();

    int cur = 0;
    for (int it = 0; it < 16; ++it) {
        if (it < 15) {
            const int nxt = cur ^ 1;
            gload16(gA0, (void*)&sA[nxt][w][0]);
            gload16(gA1, (void*)&sA[nxt][w][64]);
            gload16(gB0, (void*)&sB[nxt][w][0]);
            gload16(gB1, (void*)&sB[nxt][w][64]);
            gA0 += 32; gA1 += 32; gB0 += bstep; gB1 += bstep;
        }

        short8 aF[4], bF[4];
#pragma unroll
        for (int m = 0; m < 4; ++m) aF[m] = sA[cur][g][wr * 64 + m * 16 + fr];
#pragma unroll
        for (int n = 0; n < 4; ++n) bF[n] = sB[cur][g][wc * 64 + n * 16 + fr];
#pragma unroll
        for (int m = 0; m < 4; ++m)
#pragma unroll
            for (int n = 0; n < 4; ++n)
                acc[m][n] = __builtin_amdgcn_mfma_f32_16x16x32_bf16(
                    aF[m], bF[n], acc[m][n], 0, 0, 0);

        __syncthreads();
        cur ^= 1;
    }
    // final __syncthreads above guarantees all waves' LDS reads are drained
    // (compiler emits lgkmcnt(0) before s_barrier) -> smem reusable.

    // ---- epilogue: wave-private LDS transpose -> full-line nt stores ----
    // frag layout: acc[m][n][q] = C[wr*64 + m*16 + (lane>>4)*4 + q]
    //                              [wc*64 + n*16 + fr]           (block-local)
    const int colb = bcol + wc * 64 + fr;
    float bv[4];
#pragma unroll
    for (int n = 0; n < 4; ++n) bv[n] = bias[colb + n * 16];

    float* tw = reinterpret_cast<float*>(smem_raw) + w * 1088;  // 16 rows x 68
    const int rl = lane >> 3;       // 0..7
    const int c8 = lane & 7;        // 0..7
#pragma unroll
    for (int m = 0; m < 4; ++m) {
        // scatter one 16x64 chunk into LDS (stride 68: 2-way banks = free)
#pragma unroll
        for (int n = 0; n < 4; ++n)
#pragma unroll
            for (int q = 0; q < 4; ++q)
                tw[((lane >> 4) * 4 + q) * 68 + fr + 16 * n] = acc[m][n][q] + bv[n];
        // gather rows: each instr = 8 rows x one full 128 B line
#pragma unroll
        for (int rg = 0; rg < 2; ++rg)
#pragma unroll
            for (int h = 0; h < 2; ++h) {
                f32x4 v = *(const f32x4*)&tw[(rg * 8 + rl) * 68 + (c8 + 8 * h) * 4];
                float* dst = C + (size_t)(brow + wr * 64 + m * 16 + rg * 8 + rl) * NTOT
                               + bcol + wc * 64 + (c8 + 8 * h) * 4;
                __builtin_nontemporal_store(v, (f32x4*)dst);
            }
    }
}

extern "C" void kernel_launch(void* const* d_in, const int* in_sizes, int n_in,
                              void* d_out, int out_size, void* d_ws, size_t ws_size,
                              hipStream_t stream) {
    const float* x = (const float*)d_in[0];
    const float* W = (const float*)d_in[1];
    const float* b = (const float*)d_in[2];
    float* out = (float*)d_out;

    unsigned short* xb = (unsigned short*)d_ws;               // 4 MB
    unsigned short* wp = xb + (size_t)BATCH * D_IN;           // +33.7 MB

    convx_kernel<<<(BATCH * D_IN / 8) / 256, 256, 0, stream>>>(x, xb);
    convw_kernel<<<((D_IN / 8) * NTOT) / 256, 256, 0, stream>>>(W, wp);
    gemm_kernel<<<NWG_GEMM, 256, 0, stream>>>(xb, wp, b, out);
}